// Round 11
// baseline (199.442 us; speedup 1.0000x reference)
//
#include <hip/hip_runtime.h>
#include <math.h>

// FrequencyAwareHierarchicalEmbedding, MI355X/gfx950 — round 11
//
// B*L = 409600, D = 128, H = 32.
// d_in: fine_ids i32, coarse_ids i32, fine_W[1000001*128] f32,
//       coarse_W[10001*128] f32, freq_W[1000001] f32, W1[257*32], b1[32],
//       W2[32], b2[1].
// d_out: fused[BL*128] f32, then adjusted_gate[BL] f32.
//
// Round-11 = round 9 (118.6us, best) + two register-economy changes:
//  * Blend from PACKED bf16 row pk[16] (16 VGPRs) instead of f32 rv[16]
//    (32 VGPRs): rv dies right after pack -> peak live registers drop ~16.
//    (r10 verified numerics: absmax unchanged at 0.00195.)
//  * Occupancy 4 -> 5 blocks/CU (launch_bounds(256,5), ~102 VGPR cap):
//    25% more waves/SIMD -> more fine-row gathers in flight (TLP hides the
//    ~900cy HBM gather latency) with NO per-wave pipeline registers — the
//    r10 idea done via occupancy instead of depth (r10's rvN+pk+bfr spilled).
//  * NO cross-tile prefetch (that was the r10 spill source).
//  * Retained: single-pass, barrier-free wave-private structure, hc
//    precompute, W1 B-fragments in 32 VGPRs, XOR-swizzled LDS repack,
//    shfl_xor butterfly epilogue, nontemporal stores.

#define DD 128
#define HH 32

typedef float  f32x2  __attribute__((ext_vector_type(2)));
typedef float  f32x4  __attribute__((ext_vector_type(4)));
typedef short  bf16x8 __attribute__((ext_vector_type(8)));

__device__ __forceinline__ float sigmoid_f(float x) {
    return 1.0f / (1.0f + expf(-x));
}

__device__ __forceinline__ unsigned short bf16_rne(float x) {
    union { float f; unsigned u; } c; c.f = x;
    unsigned u = c.u + 0x7fffu + ((c.u >> 16) & 1u);
    return (unsigned short)(u >> 16);
}

// ---------------------------------------------------------------- kernel A --
__global__ __launch_bounds__(256) void coarse_mlp_kernel(
    const float* __restrict__ coarse_W,
    const float* __restrict__ W1,
    const float* __restrict__ b1,
    float* __restrict__ hc,
    int nCoarse)
{
    const int t = blockIdx.x * 256 + threadIdx.x;
    if (t >= nCoarse * HH) return;
    const int r = t >> 5;
    const int j = t & 31;
    const float* __restrict__ row = coarse_W + (size_t)r * DD;
    const float* __restrict__ w   = W1 + DD * HH + j;   // coarse rows of W1
    float acc = b1[j];
    #pragma unroll 8
    for (int i = 0; i < DD; ++i)
        acc = fmaf(row[i], w[i * HH], acc);
    hc[t] = acc;
}

// ---------------------------------------------------------------- kernel B --
__global__ __launch_bounds__(256, 5) void fused_kernel(
    const int*   __restrict__ fine_ids,
    const int*   __restrict__ coarse_ids,
    const float* __restrict__ fine_W,
    const float* __restrict__ coarse_W,
    const float* __restrict__ freq_W,
    const float* __restrict__ W1,
    const float* __restrict__ W2,
    const float* __restrict__ b2,
    const float* __restrict__ hc,
    float* __restrict__ out_fused,
    float* __restrict__ out_gate)
{
    __shared__ __align__(16) unsigned int sX[4][1024];  // 4KB per wave, private
    __shared__ float s_fw[256];
    __shared__ int   s_if[256];
    __shared__ int   s_ic[256];

    const int tid  = threadIdx.x;
    const int lane = tid & 63;
    const int wave = tid >> 6;
    const int P0   = (int)blockIdx.x * 256;

    const int jlo = lane & 15;
    const int kg  = lane >> 4;          // 0..3

    // ---- metadata (each wave writes & later reads ONLY its own 64 slots) --
    {
        const int p = P0 + tid;
        const int idf = fine_ids[p];
        s_if[tid] = idf;
        s_ic[tid] = coarse_ids[p];
        s_fw[tid] = sigmoid_f(freq_W[idf]);
    }

    // ---- W1 fine-half B-fragments -> 32 VGPRs, held all kernel ----------
    bf16x8 bfr[2][4];
    #pragma unroll
    for (int n = 0; n < 2; ++n)
        #pragma unroll
        for (int ks = 0; ks < 4; ++ks)
            #pragma unroll
            for (int i = 0; i < 8; ++i) {
                const int k = ks * 32 + kg * 8 + i;
                bfr[n][ks][i] = (short)bf16_rne(W1[k * HH + jlo + 16 * n]);
            }

    // per-lane epilogue constants
    const float w256_0 = W1[2 * DD * HH + jlo];
    const float w256_1 = W1[2 * DD * HH + jlo + 16];
    const float W2_0   = W2[jlo];
    const float W2_1   = W2[jlo + 16];
    const float b2v    = b2[0];

    char* const swave = (char*)&sX[wave][0];
    const int wbase = wave * 64;        // wave's first local position

    // ---- main loop: 4 tiles of 16 rows, fully wave-independent ----------
    #pragma unroll 1
    for (int it = 0; it < 4; ++it) {
        const int base = wbase + it * 16;

        // 1. load 16 fine rows (f32, coalesced) and pack to bf16 at once;
        //    the f32 registers die here -> low peak pressure.
        unsigned pk[16];
        #pragma unroll
        for (int i = 0; i < 16; ++i) {
            const int idf = s_if[base + i];
            const float2 v = *(const float2*)(fine_W + (size_t)idf * DD + 2 * lane);
            pk[i] = (unsigned)bf16_rne(v.x) | ((unsigned)bf16_rne(v.y) << 16);
        }

        // 2. swizzled ds_write into the wave-private region
        #pragma unroll
        for (int i = 0; i < 16; ++i)
            *(unsigned*)(swave + i * 256 + ((4 * lane) ^ ((i & 7) << 4))) = pk[i];

        // 3. MFMA: X(16x128) @ W1fine(128x32)
        f32x4 acc0 = {0.f, 0.f, 0.f, 0.f};
        f32x4 acc1 = {0.f, 0.f, 0.f, 0.f};
        #pragma unroll
        for (int ks = 0; ks < 4; ++ks) {
            const bf16x8 a = *(const bf16x8*)(swave
                + jlo * 256 + ((kg * 16 + ks * 64) ^ ((jlo & 7) << 4)));
            acc0 = __builtin_amdgcn_mfma_f32_16x16x32_bf16(a, bfr[0][ks], acc0, 0, 0, 0);
            acc1 = __builtin_amdgcn_mfma_f32_16x16x32_bf16(a, bfr[1][ks], acc1, 0, 0, 0);
        }

        // 4. epilogue: + hc + freq row, relu, @W2, butterfly, sigmoid
        float adjv[4];
        #pragma unroll
        for (int r = 0; r < 4; ++r) {
            const int posl = base + kg * 4 + r;
            const int idc  = s_ic[posl];
            const float fw = s_fw[posl];
            const float* __restrict__ hcrow = hc + idc * HH;
            const float v0 = acc0[r] + hcrow[jlo]      + w256_0 * fw;
            const float v1 = acc1[r] + hcrow[jlo + 16] + w256_1 * fw;
            float tr = fmaxf(v0, 0.f) * W2_0 + fmaxf(v1, 0.f) * W2_1;
            tr += __shfl_xor(tr, 1);
            tr += __shfl_xor(tr, 2);
            tr += __shfl_xor(tr, 4);
            tr += __shfl_xor(tr, 8);
            adjv[r] = sigmoid_f(tr + b2v) * fw;       // uniform across jlo group
            if (jlo == r)
                __builtin_nontemporal_store(adjv[r], out_gate + P0 + posl);
        }

        // 5. blend from pk (bf16 fine) + coarse gather, nt store
        #pragma unroll
        for (int i = 0; i < 16; ++i) {
            const float a = __shfl(adjv[i & 3], ((i >> 2) << 4) + (i & 3));
            const int idc = s_ic[base + i];
            const float2 c2 = *(const float2*)(coarse_W + (size_t)idc * DD + 2 * lane);
            const float fx = __uint_as_float(pk[i] << 16);
            const float fy = __uint_as_float(pk[i] & 0xffff0000u);
            f32x2 o;
            o.x = fmaf(a, fx - c2.x, c2.x);
            o.y = fmaf(a, fy - c2.y, c2.y);
            f32x2* dst = (f32x2*)(out_fused + (size_t)(P0 + base + i) * DD + 2 * lane);
            __builtin_nontemporal_store(o, dst);      // 512B/row, coalesced
        }
    }
}

// ------------------------------------------------------------------- launch --
extern "C" void kernel_launch(void* const* d_in, const int* in_sizes, int n_in,
                              void* d_out, int out_size, void* d_ws, size_t ws_size,
                              hipStream_t stream) {
    const int*   fine_ids   = (const int*)  d_in[0];
    const int*   coarse_ids = (const int*)  d_in[1];
    const float* fine_W     = (const float*)d_in[2];
    const float* coarse_W   = (const float*)d_in[3];
    const float* freq_W     = (const float*)d_in[4];
    const float* W1         = (const float*)d_in[5];
    const float* b1         = (const float*)d_in[6];
    const float* W2         = (const float*)d_in[7];
    const float* b2         = (const float*)d_in[8];

    const int n       = in_sizes[0];          // B*L = 409600 (divisible by 256)
    const int nCoarse = in_sizes[3] / DD;     // 10001

    float* out_fused = (float*)d_out;
    float* out_gate  = (float*)d_out + (size_t)n * DD;
    float* hc        = (float*)d_ws;          // nCoarse*32 floats = 1.28 MB

    coarse_mlp_kernel<<<dim3((nCoarse * HH + 255) / 256), dim3(256), 0, stream>>>(
        coarse_W, W1, b1, hc, nCoarse);

    fused_kernel<<<dim3(n / 256), dim3(256), 0, stream>>>(
        fine_ids, coarse_ids, fine_W, coarse_W, freq_W,
        W1, W2, b2, hc, out_fused, out_gate);
}

// Round 12
// 119.329 us; speedup vs baseline: 1.6714x; 1.6714x over previous
//
#include <hip/hip_runtime.h>
#include <math.h>

// FrequencyAwareHierarchicalEmbedding, MI355X/gfx950 — round 12
//
// B*L = 409600, D = 128, H = 32.
// d_in: fine_ids i32, coarse_ids i32, fine_W[1000001*128] f32,
//       coarse_W[10001*128] f32, freq_W[1000001] f32, W1[257*32], b1[32],
//       W2[32], b2[1].
// d_out: fused[BL*128] f32, then adjusted_gate[BL] f32.
//
// Round-12 = EXACT round-9 structure/config (118.6us best, launch_bounds(256,4))
// with ONE isolated change:
//  * pk-blend: blend from the packed bf16 row pk[16] (16 VGPRs) instead of
//    f32 rv[16] (32 VGPRs). Peak live registers drop ~16; the freed regs let
//    the compiler deepen its own scheduling of the (fully unrolled) coarse
//    and hc loads. Numerics proven in r10/r11: absmax 0.00195 (passes).
//  * r10's cross-tile prefetch and r11's (256,5) cap are both REVERTED —
//    each independently caused spill regressions (172us / 199us).
//  * Retained from r9: single-pass, barrier-free wave-private structure,
//    hc precompute, W1 B-fragments in 32 VGPRs, XOR-swizzled LDS repack,
//    shfl_xor butterfly epilogue, nontemporal stores.

#define DD 128
#define HH 32

typedef float  f32x2  __attribute__((ext_vector_type(2)));
typedef float  f32x4  __attribute__((ext_vector_type(4)));
typedef short  bf16x8 __attribute__((ext_vector_type(8)));

__device__ __forceinline__ float sigmoid_f(float x) {
    return 1.0f / (1.0f + expf(-x));
}

__device__ __forceinline__ unsigned short bf16_rne(float x) {
    union { float f; unsigned u; } c; c.f = x;
    unsigned u = c.u + 0x7fffu + ((c.u >> 16) & 1u);
    return (unsigned short)(u >> 16);
}

// ---------------------------------------------------------------- kernel A --
__global__ __launch_bounds__(256) void coarse_mlp_kernel(
    const float* __restrict__ coarse_W,
    const float* __restrict__ W1,
    const float* __restrict__ b1,
    float* __restrict__ hc,
    int nCoarse)
{
    const int t = blockIdx.x * 256 + threadIdx.x;
    if (t >= nCoarse * HH) return;
    const int r = t >> 5;
    const int j = t & 31;
    const float* __restrict__ row = coarse_W + (size_t)r * DD;
    const float* __restrict__ w   = W1 + DD * HH + j;   // coarse rows of W1
    float acc = b1[j];
    #pragma unroll 8
    for (int i = 0; i < DD; ++i)
        acc = fmaf(row[i], w[i * HH], acc);
    hc[t] = acc;
}

// ---------------------------------------------------------------- kernel B --
__global__ __launch_bounds__(256, 4) void fused_kernel(
    const int*   __restrict__ fine_ids,
    const int*   __restrict__ coarse_ids,
    const float* __restrict__ fine_W,
    const float* __restrict__ coarse_W,
    const float* __restrict__ freq_W,
    const float* __restrict__ W1,
    const float* __restrict__ W2,
    const float* __restrict__ b2,
    const float* __restrict__ hc,
    float* __restrict__ out_fused,
    float* __restrict__ out_gate)
{
    __shared__ __align__(16) unsigned int sX[4][1024];  // 4KB per wave, private
    __shared__ float s_fw[256];
    __shared__ int   s_if[256];
    __shared__ int   s_ic[256];

    const int tid  = threadIdx.x;
    const int lane = tid & 63;
    const int wave = tid >> 6;
    const int P0   = (int)blockIdx.x * 256;

    const int jlo = lane & 15;
    const int kg  = lane >> 4;          // 0..3

    // ---- metadata (each wave writes & later reads ONLY its own 64 slots) --
    {
        const int p = P0 + tid;
        const int idf = fine_ids[p];
        s_if[tid] = idf;
        s_ic[tid] = coarse_ids[p];
        s_fw[tid] = sigmoid_f(freq_W[idf]);
    }

    // ---- W1 fine-half B-fragments -> 32 VGPRs, held all kernel ----------
    bf16x8 bfr[2][4];
    #pragma unroll
    for (int n = 0; n < 2; ++n)
        #pragma unroll
        for (int ks = 0; ks < 4; ++ks)
            #pragma unroll
            for (int i = 0; i < 8; ++i) {
                const int k = ks * 32 + kg * 8 + i;
                bfr[n][ks][i] = (short)bf16_rne(W1[k * HH + jlo + 16 * n]);
            }

    // per-lane epilogue constants
    const float w256_0 = W1[2 * DD * HH + jlo];
    const float w256_1 = W1[2 * DD * HH + jlo + 16];
    const float W2_0   = W2[jlo];
    const float W2_1   = W2[jlo + 16];
    const float b2v    = b2[0];

    char* const swave = (char*)&sX[wave][0];
    const int wbase = wave * 64;        // wave's first local position

    // ---- main loop: 4 tiles of 16 rows, fully wave-independent ----------
    #pragma unroll 1
    for (int it = 0; it < 4; ++it) {
        const int base = wbase + it * 16;

        // 1. load 16 fine rows (f32, coalesced) and pack to bf16; the f32
        //    load registers die here -> low peak pressure.
        unsigned pk[16];
        #pragma unroll
        for (int i = 0; i < 16; ++i) {
            const int idf = s_if[base + i];
            const float2 v = *(const float2*)(fine_W + (size_t)idf * DD + 2 * lane);
            pk[i] = (unsigned)bf16_rne(v.x) | ((unsigned)bf16_rne(v.y) << 16);
        }

        // 2. swizzled ds_write into the wave-private region
        #pragma unroll
        for (int i = 0; i < 16; ++i)
            *(unsigned*)(swave + i * 256 + ((4 * lane) ^ ((i & 7) << 4))) = pk[i];

        // 3. MFMA: X(16x128) @ W1fine(128x32)
        f32x4 acc0 = {0.f, 0.f, 0.f, 0.f};
        f32x4 acc1 = {0.f, 0.f, 0.f, 0.f};
        #pragma unroll
        for (int ks = 0; ks < 4; ++ks) {
            const bf16x8 a = *(const bf16x8*)(swave
                + jlo * 256 + ((kg * 16 + ks * 64) ^ ((jlo & 7) << 4)));
            acc0 = __builtin_amdgcn_mfma_f32_16x16x32_bf16(a, bfr[0][ks], acc0, 0, 0, 0);
            acc1 = __builtin_amdgcn_mfma_f32_16x16x32_bf16(a, bfr[1][ks], acc1, 0, 0, 0);
        }

        // 4. epilogue: + hc + freq row, relu, @W2, butterfly, sigmoid
        float adjv[4];
        #pragma unroll
        for (int r = 0; r < 4; ++r) {
            const int posl = base + kg * 4 + r;
            const int idc  = s_ic[posl];
            const float fw = s_fw[posl];
            const float* __restrict__ hcrow = hc + idc * HH;
            const float v0 = acc0[r] + hcrow[jlo]      + w256_0 * fw;
            const float v1 = acc1[r] + hcrow[jlo + 16] + w256_1 * fw;
            float tr = fmaxf(v0, 0.f) * W2_0 + fmaxf(v1, 0.f) * W2_1;
            tr += __shfl_xor(tr, 1);
            tr += __shfl_xor(tr, 2);
            tr += __shfl_xor(tr, 4);
            tr += __shfl_xor(tr, 8);
            adjv[r] = sigmoid_f(tr + b2v) * fw;       // uniform across jlo group
            if (jlo == r)
                __builtin_nontemporal_store(adjv[r], out_gate + P0 + posl);
        }

        // 5. blend from pk (bf16 fine) + coarse gather, nt store
        #pragma unroll
        for (int i = 0; i < 16; ++i) {
            const float a = __shfl(adjv[i & 3], ((i >> 2) << 4) + (i & 3));
            const int idc = s_ic[base + i];
            const float2 c2 = *(const float2*)(coarse_W + (size_t)idc * DD + 2 * lane);
            const float fx = __uint_as_float(pk[i] << 16);
            const float fy = __uint_as_float(pk[i] & 0xffff0000u);
            f32x2 o;
            o.x = fmaf(a, fx - c2.x, c2.x);
            o.y = fmaf(a, fy - c2.y, c2.y);
            f32x2* dst = (f32x2*)(out_fused + (size_t)(P0 + base + i) * DD + 2 * lane);
            __builtin_nontemporal_store(o, dst);      // 512B/row, coalesced
        }
    }
}

// ------------------------------------------------------------------- launch --
extern "C" void kernel_launch(void* const* d_in, const int* in_sizes, int n_in,
                              void* d_out, int out_size, void* d_ws, size_t ws_size,
                              hipStream_t stream) {
    const int*   fine_ids   = (const int*)  d_in[0];
    const int*   coarse_ids = (const int*)  d_in[1];
    const float* fine_W     = (const float*)d_in[2];
    const float* coarse_W   = (const float*)d_in[3];
    const float* freq_W     = (const float*)d_in[4];
    const float* W1         = (const float*)d_in[5];
    const float* b1         = (const float*)d_in[6];
    const float* W2         = (const float*)d_in[7];
    const float* b2         = (const float*)d_in[8];

    const int n       = in_sizes[0];          // B*L = 409600 (divisible by 256)
    const int nCoarse = in_sizes[3] / DD;     // 10001

    float* out_fused = (float*)d_out;
    float* out_gate  = (float*)d_out + (size_t)n * DD;
    float* hc        = (float*)d_ws;          // nCoarse*32 floats = 1.28 MB

    coarse_mlp_kernel<<<dim3((nCoarse * HH + 255) / 256), dim3(256), 0, stream>>>(
        coarse_W, W1, b1, hc, nCoarse);

    fused_kernel<<<dim3(n / 256), dim3(256), 0, stream>>>(
        fine_ids, coarse_ids, fine_W, coarse_W, freq_W,
        W1, W2, b2, hc, out_fused, out_gate);
}